// Round 1
// baseline (238.542 us; speedup 1.0000x reference)
//
#include <hip/hip_runtime.h>
#include <stdint.h>

#define NR 16
#define NC 80
#define NA 8400
#define NB 16
#define KPRE 1024
#define MAXDET 300
#define CONF_T 0.25f
#define IOU_THR 0.45f
#define CAP 2048  // LDS-resident compacted-candidate cap (M~1300 typ.)

// Robust scalar read: harness passes python ints most likely as int32; fall
// back to float32 reinterpretation if the int pattern is implausible.
__device__ __forceinline__ float read_dim(const void* p) {
  int iv = *(const int*)p;
  return (iv > 0 && iv < (1 << 20)) ? (float)iv : *(const float*)p;
}

__device__ __forceinline__ const float* level_ptr(const float* p0, const float* p1,
                                                  const float* p2, int a, int& HW,
                                                  int& W, float& stride, int& m) {
  if (a < 6400)      { HW = 6400; W = 80; stride = 8.f;  m = a;        return p0; }
  else if (a < 8000) { HW = 1600; W = 40; stride = 16.f; m = a - 6400; return p1; }
  else               { HW = 400;  W = 20; stride = 32.f; m = a - 8000; return p2; }
}

__device__ __forceinline__ uint64_t readlane64(uint64_t v, int lane) {
  uint32_t lo = (uint32_t)__builtin_amdgcn_readlane((int)(uint32_t)v, lane);
  uint32_t hi = (uint32_t)__builtin_amdgcn_readlane((int)(uint32_t)(v >> 32), lane);
  return ((uint64_t)hi << 32) | lo;
}

// ---------------------------------------------------------------- decode ----
// 4 threads per anchor (quad): thread k owns DFL dim k (16 ch) + class
// channels ch%4==k (20 ch). 537600 threads = 8400 waves ~ 33 waves/CU.
// (R8 lesson: do NOT run this in a 256-block cooperative kernel — decode is
// latency-bound and needs the full wave oversubscription.)
__global__ __launch_bounds__(256) void k_decode(
    const float* __restrict__ p0, const float* __restrict__ p1,
    const float* __restrict__ p2, const void* __restrict__ hp,
    const void* __restrict__ wp, float4* __restrict__ boxes,
    uint32_t* __restrict__ keys, int* __restrict__ labels) {
  int gid = blockIdx.x * 256 + threadIdx.x;  // grid exactly NB*NA*4
  int aid = gid >> 2, k = gid & 3;
  int b = aid / NA, a = aid - b * NA;
  int HW, W, m; float stride;
  const float* p = level_ptr(p0, p1, p2, a, HW, W, stride, m);
  const float* base = p + (size_t)b * (4 * NR + NC) * HW + m;

  // DFL dim k: softmax-expectation over 16 bins
  float v[NR]; float mx = -3.4e38f;
#pragma unroll
  for (int r = 0; r < NR; ++r) { v[r] = base[(size_t)(k * NR + r) * HW]; mx = fmaxf(mx, v[r]); }
  float se = 0.f, sn = 0.f;
#pragma unroll
  for (int r = 0; r < NR; ++r) { float e = expf(v[r] - mx); se += e; sn += e * (float)r; }
  float dk = sn / se * stride;

  // class argmax over channels (4c + k), c=0..19 (raw logits; sigmoid monotone)
  float ml = -3.4e38f; int mc = NC;
#pragma unroll 4
  for (int c = 0; c < 20; ++c) {
    int ch = 4 * c + k;
    float vv = base[(size_t)(4 * NR + ch) * HW];
    if (vv > ml) { ml = vv; mc = ch; }
  }
  // quad reduce: strict max, tie -> smaller channel (reference first-argmax)
#pragma unroll
  for (int off = 1; off < 4; off <<= 1) {
    float ov = __shfl_xor(ml, off);
    int oc = __shfl_xor(mc, off);
    if (ov > ml || (ov == ml && oc < mc)) { ml = ov; mc = oc; }
  }
  // exchange the four DFL distances within the quad
  int lane = threadIdx.x & 63;
  int bl = lane & ~3;
  float dl = __shfl(dk, bl), dt = __shfl(dk, bl + 1);
  float dr = __shfl(dk, bl + 2), db = __shfl(dk, bl + 3);

  if (k == 0) {
    int x = m % W, y = m / W;
    float cx = ((float)x + 0.5f) * stride, cy = ((float)y + 0.5f) * stride;
    float hx = read_dim(wp) - 1.f, hy = read_dim(hp) - 1.f;
    boxes[aid] = make_float4(fminf(fmaxf(cx - dl, 0.f), hx),
                             fminf(fmaxf(cy - dt, 0.f), hy),
                             fminf(fmaxf(cx + dr, 0.f), hx),
                             fminf(fmaxf(cy + db, 0.f), hy));
  } else if (k == 1) {
    float smax = 1.f / (1.f + expf(-ml));
    float s = smax > CONF_T ? smax : -1.0f;
    uint32_t bt = __float_as_uint(s);
    keys[aid] = (bt & 0x80000000u) ? ~bt : (bt | 0x80000000u);  // sortable
  } else if (k == 2) {
    labels[aid] = mc;
  }
}

// ------- fused radix threshold + compact + exact rank + gather (per img) ----
// R6 lesson amended: the O(M^2) rank IS fusable once the compacted set lives
// in LDS (M ~ 1300 << CAP=2048). Kills the k_rank2 dispatch + cmp round-trip.
// 16 per-wave hists (keys share hot top bytes; fewer hists serialize more).
__global__ __launch_bounds__(1024) void k_selrank(
    const uint32_t* __restrict__ keys, const float4* __restrict__ boxes,
    const int* __restrict__ labels, uint64_t* __restrict__ cmp,
    float4* __restrict__ selbox, float4* __restrict__ selboff,
    float* __restrict__ selscore, int* __restrict__ sellab) {
  __shared__ __align__(16) uint32_t skeys[NA];  // 33600 B
  __shared__ uint32_t whist[16][256];           // 16 KB, one hist per wave
  __shared__ uint32_t hsum[256], ssuf[256];
  __shared__ uint64_t scmp[CAP];                // 16 KB compacted candidates
  __shared__ int s_b1, s_rem, s_t16, s_cnt;
  int img = blockIdx.x, tid = threadIdx.x;
  int w = tid >> 6, lane = tid & 63;
  const uint4* kb4 = (const uint4*)(keys + (size_t)img * NA);  // NA/4 = 2100
  for (int j = tid; j < NA / 4; j += 1024) ((uint4*)skeys)[j] = kb4[j];
  if (tid == 0) s_cnt = 0;

  // ---- pass 1: digit = key >> 24 ----
  for (int j = tid; j < 16 * 256; j += 1024) ((uint32_t*)whist)[j] = 0;
  __syncthreads();
  for (int j = tid; j < NA; j += 1024) atomicAdd(&whist[w][skeys[j] >> 24], 1u);
  __syncthreads();
  if (tid < 256) { uint32_t s = 0; for (int i = 0; i < 16; ++i) s += whist[i][tid]; hsum[tid] = s; }
  __syncthreads();
  if (tid < 256) { uint32_t s = 0; for (int j = tid; j < 256; ++j) s += hsum[j]; ssuf[tid] = s; }
  __syncthreads();
  if (tid < 256) {
    uint32_t ab = (tid == 255) ? 0u : ssuf[tid + 1];
    if (ssuf[tid] >= KPRE && ab < KPRE) { s_b1 = tid; s_rem = KPRE - (int)ab; }
  }
  __syncthreads();
  int b1 = s_b1, rem = s_rem;
  __syncthreads();

  // ---- pass 2: digit = (key>>16)&0xFF restricted to (key>>24)==b1 ----
  for (int j = tid; j < 16 * 256; j += 1024) ((uint32_t*)whist)[j] = 0;
  __syncthreads();
  for (int j = tid; j < NA; j += 1024) {
    uint32_t k = skeys[j];
    if ((int)(k >> 24) == b1) atomicAdd(&whist[w][(k >> 16) & 0xFF], 1u);
  }
  __syncthreads();
  if (tid < 256) { uint32_t s = 0; for (int i = 0; i < 16; ++i) s += whist[i][tid]; hsum[tid] = s; }
  __syncthreads();
  if (tid < 256) { uint32_t s = 0; for (int j = tid; j < 256; ++j) s += hsum[j]; ssuf[tid] = s; }
  __syncthreads();
  if (tid < 256) {
    int ab = (tid == 255) ? 0 : (int)ssuf[tid + 1];
    if ((int)ssuf[tid] >= rem && ab < rem) s_t16 = (b1 << 8) | tid;
  }
  __syncthreads();
  uint32_t t16 = (uint32_t)s_t16;

  // ---- compact into LDS (global cmp only as >CAP overflow fallback) ----
  for (int j0 = 0; j0 < NA; j0 += 1024) {
    int j = j0 + tid;
    uint32_t k = (j < NA) ? skeys[j] : 0;
    bool pass = (j < NA) && ((k >> 16) >= t16);
    uint64_t mask = __ballot(pass);
    int pre = __popcll(mask & ((1ull << lane) - 1ull));
    int wc = __popcll(mask);
    int base = 0;
    if (lane == 0) base = wc ? atomicAdd(&s_cnt, wc) : 0;
    base = __shfl(base, 0);
    if (pass) {
      int slot = base + pre;
      uint64_t v = ((uint64_t)k << 32) | (uint64_t)(0xFFFFFFFFu - (uint32_t)j);
      if (slot < CAP) scmp[slot] = v;
      else cmp[(size_t)img * NA + slot] = v;
    }
  }
  __threadfence_block();
  __syncthreads();

  // ---- exact rank on top-M set + winner gather ----
  // Compacted set == exact top-M keys (upward-closed at bin granularity), so
  // local rank == global rank. u64 keys are unique (low word = ~j).
  int M = s_cnt; if (M > NA) M = NA;
  int lim = M < CAP ? M : CAP;
  for (int c = tid; c < M; c += 1024) {
    uint64_t kc = (c < CAP) ? scmp[c] : cmp[(size_t)img * NA + c];
    int rank = 0;
    int j = 0;
    for (; j + 4 <= lim; j += 4) {
      rank += (int)(scmp[j] > kc) + (int)(scmp[j + 1] > kc) +
              (int)(scmp[j + 2] > kc) + (int)(scmp[j + 3] > kc);
    }
    for (; j < lim; ++j) rank += (int)(scmp[j] > kc);
    for (j = CAP; j < M; ++j) rank += (int)(cmp[(size_t)img * NA + j] > kc);
    if (rank < KPRE) {
      int a = (int)(0xFFFFFFFFu - (uint32_t)kc);
      uint32_t uk = (uint32_t)(kc >> 32);
      uint32_t bits = (uk & 0x80000000u) ? (uk & 0x7FFFFFFFu) : ~uk;
      float s = __uint_as_float(bits);
      int lab = labels[img * NA + a];
      float4 bx = boxes[(size_t)img * NA + a];
      float off = (float)lab * 4096.0f;  // replicate reference CLS_OFFSET fp math
      int o = img * KPRE + rank;
      selbox[o] = bx;
      selboff[o] = make_float4(bx.x + off, bx.y + off, bx.z + off, bx.w + off);
      selscore[o] = s;
      sellab[o] = lab;
    }
  }
}

// ----------------------------------------------------- IoU suppression bits -
// Output layout TRANSPOSED: rowmask[img][w][i] (w=word 0..15, i=row 0..1023)
// so k_scan's per-chunk staging loads are coalesced.
// Inner loop rotated per wave-quarter: the 4 concurrent bb[] b128 reads in a
// wave are 1024 B apart (same bank). jb = (jj + (w&3)) & 63 puts them on
// disjoint 4-bank spans -> conflict-free (R8 PMC: 1.6e7 conflict cycles).
// Areas precomputed into sar[] (bit-identical expression; LDS read is a
// 16-lane broadcast) -> 3 fewer VALU ops per pair.
__global__ __launch_bounds__(256) void k_iou(const float4* __restrict__ selboff,
                                             uint64_t* __restrict__ rowmask) {
  __shared__ float4 bb[KPRE];
  __shared__ float sar[KPRE];
  int img = blockIdx.y;
  for (int j = threadIdx.x; j < KPRE; j += 256) {
    float4 v = selboff[img * KPRE + j];
    bb[j] = v;
    sar[j] = (v.z - v.x) * (v.w - v.y);
  }
  __syncthreads();
  int i = blockIdx.x * 16 + (threadIdx.x & 15);
  int w = threadIdx.x >> 4;
  int rot = w & 3;
  float4 bi = bb[i];
  float ai = sar[i];
  uint64_t bits = 0;
  for (int jj = 0; jj < 64; ++jj) {
    int jb = (jj + rot) & 63;
    int j = w * 64 + jb;
    float4 bj = bb[j];
    float lx = fmaxf(bi.x, bj.x), ly = fmaxf(bi.y, bj.y);
    float rx = fminf(bi.z, bj.z), ry = fminf(bi.w, bj.w);
    float iw = fmaxf(rx - lx, 0.f), ih = fmaxf(ry - ly, 0.f);
    float inter = iw * ih;
    float aj = sar[j];
    float iou = inter / (ai + aj - inter + 1e-7f);
    bits |= (uint64_t)((iou > IOU_THR) && (j != i)) << jb;
  }
  rowmask[(size_t)img * 16384 + (size_t)w * 1024 + i] = bits;
}

// --------------------------- single-wave barrier-free greedy scan (SALU) ----
// remv accumulation now 4-way parallel: lane l covers word (l&15), handling
// every 4th kept row (sub = l>>4). Consumption ORs the 4 partials via
// readlane64. Also: inner loop breaks the moment n hits MAXDET, and the remv
// update is skipped entirely on the final chunk.
__global__ __launch_bounds__(64) void k_scan(
    const uint64_t* __restrict__ rowmask, const float4* __restrict__ selbox,
    const float* __restrict__ selscore, const int* __restrict__ sellab,
    float* __restrict__ out) {
  __shared__ float lsc[KPRE];
  __shared__ uint64_t buf[2][16 * 65];  // [w*65+ii], pad avoids bank conflicts
  __shared__ int keepidx[MAXDET];
  int img = blockIdx.x, lane = threadIdx.x;
  int wsel = lane & 15, sub = lane >> 4;
  const uint64_t* g = rowmask + (size_t)img * 16384;

  for (int j = lane; j < KPRE; j += 64) lsc[j] = selscore[img * KPRE + j];

  // stage chunk 0
  {
    uint64_t r0[16];
#pragma unroll
    for (int t = 0; t < 16; ++t) r0[t] = g[t * 1024 + lane];
#pragma unroll
    for (int t = 0; t < 16; ++t) buf[0][t * 65 + lane] = r0[t];
  }
  asm volatile("" ::: "memory");

  uint64_t remv = 0;
  int n = 0;
  for (int c = 0; c < 16; ++c) {
    uint64_t rn[16];
    if (c + 1 < 16) {  // prefetch next chunk (global, overlapped with scan)
#pragma unroll
      for (int t = 0; t < 16; ++t) rn[t] = g[t * 1024 + (c + 1) * 64 + lane];
    }
    const uint64_t* B = buf[c & 1];
    uint64_t m = B[c * 65 + lane];           // self-chunk word of row `lane`
    float sc = lsc[c * 64 + lane];
    uint64_t vmask = __ballot(sc > CONF_T);  // valid (conf-passing) bitmap
    uint64_t cur = readlane64(remv, c) | readlane64(remv, c + 16) |
                   readlane64(remv, c + 32) | readlane64(remv, c + 48);
    uint64_t kmask = 0;
#pragma unroll
    for (int ii = 0; ii < 64; ++ii) {
      if (((vmask >> ii) & 1ull) && !((cur >> ii) & 1ull)) {
        cur |= readlane64(m, ii);
        kmask |= (1ull << ii);
        if (lane == 0 && n < MAXDET) keepidx[n] = c * 64 + ii;
        n++;
        if (n >= MAXDET) break;
      }
    }
    // stop: last candidate of chunk invalid => all later invalid (sorted)
    bool done = !((vmask >> 63) & 1ull) || n >= MAXDET;
    if (!done) {
      // batch remv update for future chunks, 4-way parallel per word
      uint64_t km = kmask;
      int t = 0;
      while (km) {
        int ii2 = __ffsll((unsigned long long)km) - 1;
        km &= km - 1;
        if ((t & 3) == sub) remv |= B[wsel * 65 + ii2];
        ++t;
      }
    }
    if (done) break;
    if (c + 1 < 16) {
#pragma unroll
      for (int t = 0; t < 16; ++t) buf[(c + 1) & 1][t * 65 + lane] = rn[t];
    }
    asm volatile("" ::: "memory");
  }

  // parallel output pass
  asm volatile("" ::: "memory");
  float* ob = out;                        // (B,300,4)
  float* os = out + NB * MAXDET * 4;      // (B,300)
  float* ol = out + NB * MAXDET * 5;      // labels as float
  float* ov = out + NB * MAXDET * 6;      // valid as 0/1 float
  int nk = n < MAXDET ? n : MAXDET;
  for (int s0 = 0; s0 < MAXDET; s0 += 64) {
    int slot = s0 + lane;
    if (slot >= MAXDET) break;
    bool v = slot < nk;
    float4 bx = make_float4(0.f, 0.f, 0.f, 0.f);
    float scv = 0.f, lbv = -1.f;
    if (v) {
      int i = keepidx[slot];
      bx = selbox[img * KPRE + i];
      scv = lsc[i];
      lbv = (float)sellab[img * KPRE + i];
    }
    ((float4*)ob)[img * MAXDET + slot] = bx;
    os[img * MAXDET + slot] = scv;
    ol[img * MAXDET + slot] = lbv;
    ov[img * MAXDET + slot] = v ? 1.0f : 0.0f;
  }
}

// -------------------------------------------------------------- launcher ----
extern "C" void kernel_launch(void* const* d_in, const int* in_sizes, int n_in,
                              void* d_out, int out_size, void* d_ws, size_t ws_size,
                              hipStream_t stream) {
  const float* p0 = (const float*)d_in[0];
  const float* p1 = (const float*)d_in[1];
  const float* p2 = (const float*)d_in[2];
  const void* hp = d_in[3];
  const void* wp = d_in[4];

  // Workspace (~4.96 MB). rowmask ALIASES boxes: boxes is dead after
  // k_selrank's gather; k_iou (writer of rowmask) runs strictly after.
  char* ws = (char*)d_ws;
  float4*   boxes    = (float4*)(ws + 0);          // 2150400
  uint64_t* rowmask  = (uint64_t*)(ws + 0);        // alias: 2097152
  uint32_t* keys     = (uint32_t*)(ws + 2150400);  // 537600
  int*      labels   = (int*)(ws + 2688000);       // 537600
  float4*   selbox   = (float4*)(ws + 3225600);    // 262144
  float4*   selboff  = (float4*)(ws + 3487744);    // 262144
  float*    selscore = (float*)(ws + 3749888);     // 65536
  int*      sellab   = (int*)(ws + 3815424);       // 65536
  uint64_t* cmp      = (uint64_t*)(ws + 3881024);  // overflow fallback only

  k_decode<<<(NB * NA * 4) / 256, 256, 0, stream>>>(p0, p1, p2, hp, wp,
                                                    boxes, keys, labels);
  k_selrank<<<NB, 1024, 0, stream>>>(keys, boxes, labels, cmp,
                                     selbox, selboff, selscore, sellab);
  dim3 ig(KPRE / 16, NB);
  k_iou<<<ig, 256, 0, stream>>>(selboff, rowmask);
  k_scan<<<NB, 64, 0, stream>>>(rowmask, selbox, selscore, sellab,
                                (float*)d_out);
}